// Round 1
// baseline (3879.091 us; speedup 1.0000x reference)
//
#include <hip/hip_runtime.h>
#include <hip/hip_bf16.h>
#include <cstdint>
#include <cstddef>

// nODE: 50 Euler steps of  x <- x*(1+dt*gamma) + dt*tanh(x @ W^T + b)
// M=32768 (batch), D=512 (ODE dim), dt=1/50.
// Strategy: bf16 MFMA GEMM (m97 structure: 128x128 tile, BK=64,
// global_load_lds width-16 staging, 4 waves x (4x4) 16x16x32 mfma),
// fused epilogue (bias + fast tanh + Euler update), fp32 state ping-pong,
// bf16 state copy written by the epilogue for the next step's GEMM.

#define D_DIM 512
#define BATCH_N 32768
#define NSTEPS 50

typedef __bf16 bf16x8 __attribute__((ext_vector_type(8)));
typedef float f32x4 __attribute__((ext_vector_type(4)));

typedef __attribute__((address_space(1))) const void gv_t;
typedef __attribute__((address_space(3))) void lv_t;

__device__ __forceinline__ float bf16_bits_to_f(unsigned short u) {
    union { unsigned int i; float f; } c;
    c.i = ((unsigned int)u) << 16;
    return c.f;
}
__device__ __forceinline__ unsigned short f_to_bf16_bits(float f) {
    union { float f; unsigned int i; } c;
    c.f = f;
    unsigned int u = c.i;
    // round-to-nearest-even
    unsigned int r = (u + 0x7fffu + ((u >> 16) & 1u)) >> 16;
    return (unsigned short)r;
}

__global__ __launch_bounds__(256) void f32_to_bf16_vec4(
    const float* __restrict__ src, unsigned short* __restrict__ dst, int nv) {
    int i = blockIdx.x * blockDim.x + threadIdx.x;
    if (i < nv) {
        float4 v = ((const float4*)src)[i];
        ushort4 o;
        o.x = f_to_bf16_bits(v.x);
        o.y = f_to_bf16_bits(v.y);
        o.z = f_to_bf16_bits(v.z);
        o.w = f_to_bf16_bits(v.w);
        ((ushort4*)dst)[i] = o;
    }
}

// One Euler step:
//   y = Ain(bf16) @ Wb^T(bf16)            (MFMA, fp32 acc)
//   s = Sin (fp32 state; if null, decode from Ain bf16)
//   out = s*(1 + dt*gamma) + dt*tanh(y + bias)
//   Sout (fp32, may be null) and Aout (bf16, may be null) both get out.
__global__ __launch_bounds__(256, 2) void node_step(
    const unsigned short* __restrict__ Ain,   // bf16 state [32768][512]
    const unsigned short* __restrict__ Wb,    // bf16 W [512][512], row j = output col, col k
    const float* __restrict__ Sin,            // fp32 state (nullable)
    const float* __restrict__ bias,           // [512]
    const float* __restrict__ gamma,          // [512]
    float* __restrict__ Sout,                 // fp32 next state (nullable)
    unsigned short* __restrict__ Aout)        // bf16 next state (nullable)
{
    __shared__ unsigned short ldsA[128 * 64];
    __shared__ unsigned short ldsB[128 * 64];

    const int tid  = threadIdx.x;
    const int lane = tid & 63;
    const int w    = tid >> 6;        // wave id 0..3
    const int wm   = w & 1;           // wave m offset /64
    const int wn   = w >> 1;          // wave n offset /64
    const int l16  = lane & 15;
    const int quad = lane >> 4;

    const int bm = blockIdx.y;        // 0..255 (row block of 128)
    const int bn = blockIdx.x;        // 0..3   (col block of 128)

    const unsigned short* Ag = Ain + (size_t)bm * 128 * D_DIM;
    const unsigned short* Bg = Wb  + (size_t)bn * 128 * D_DIM;

    // Staging: tile is 128 rows x 64 k of bf16 = 16KB = 16 wave-chunks of 1KB.
    // Wave-chunk g covers rows [g*8, g*8+8); lane L handles 16B piece p = g*64+L:
    //   row = p>>3, kchunk = p&7 (8 bf16 per 16B).
    int goff[4];
    int loff[4];
#pragma unroll
    for (int i = 0; i < 4; ++i) {
        int g = i * 4 + w;
        int p = g * 64 + lane;
        goff[i] = (p >> 3) * D_DIM + (p & 7) * 8;  // elements
        loff[i] = g * 1024;                        // bytes (wave-uniform base)
    }

    f32x4 acc[4][4];
    const f32x4 zero = {0.f, 0.f, 0.f, 0.f};
#pragma unroll
    for (int a = 0; a < 4; ++a)
#pragma unroll
        for (int b = 0; b < 4; ++b) acc[a][b] = zero;

    for (int kb = 0; kb < D_DIM; kb += 64) {
        __syncthreads();   // previous compute done before overwriting LDS
#pragma unroll
        for (int i = 0; i < 4; ++i)
            __builtin_amdgcn_global_load_lds(
                (gv_t*)(Ag + goff[i] + kb),
                (lv_t*)((char*)ldsA + loff[i]), 16, 0, 0);
#pragma unroll
        for (int i = 0; i < 4; ++i)
            __builtin_amdgcn_global_load_lds(
                (gv_t*)(Bg + goff[i] + kb),
                (lv_t*)((char*)ldsB + loff[i]), 16, 0, 0);
        __syncthreads();   // drains vmcnt before barrier -> LDS staged

#pragma unroll
        for (int kh = 0; kh < 2; ++kh) {
            const int ko = kh * 32 + quad * 8;
            bf16x8 af[4], bf[4];
#pragma unroll
            for (int t = 0; t < 4; ++t)
                af[t] = *reinterpret_cast<const bf16x8*>(
                    &ldsA[(wm * 64 + t * 16 + l16) * 64 + ko]);
#pragma unroll
            for (int t = 0; t < 4; ++t)
                bf[t] = *reinterpret_cast<const bf16x8*>(
                    &ldsB[(wn * 64 + t * 16 + l16) * 64 + ko]);
#pragma unroll
            for (int tm = 0; tm < 4; ++tm)
#pragma unroll
                for (int tn = 0; tn < 4; ++tn)
                    acc[tm][tn] = __builtin_amdgcn_mfma_f32_16x16x32_bf16(
                        af[tm], bf[tn], acc[tm][tn], 0, 0, 0);
        }
    }

    // Epilogue. C/D layout (m89-verified): col = lane&15, row = quad*4 + r.
    const float dt = 1.0f / 50.0f;
    const int gr0 = bm * 128 + wm * 64 + quad * 4;
    const int gc0 = bn * 128 + wn * 64 + l16;
#pragma unroll
    for (int tn = 0; tn < 4; ++tn) {
        const int col = gc0 + tn * 16;
        const float bc = bias[col];
        const float g1 = 1.0f + dt * gamma[col];
#pragma unroll
        for (int tm = 0; tm < 4; ++tm) {
#pragma unroll
            for (int r = 0; r < 4; ++r) {
                const int row = gr0 + tm * 16 + r;
                const size_t idx = (size_t)row * D_DIM + col;
                float y = acc[tm][tn][r] + bc;
                // tanh(y) = 1 - 2/(e^{2y}+1); handles +-inf saturation cleanly
                float e = __expf(2.0f * y);
                float th = 1.0f - 2.0f * __builtin_amdgcn_rcpf(e + 1.0f);
                float s = Sin ? Sin[idx] : bf16_bits_to_f(Ain[idx]);
                float o = s * g1 + dt * th;
                if (Sout) Sout[idx] = o;
                if (Aout) Aout[idx] = f_to_bf16_bits(o);
            }
        }
    }
}

extern "C" void kernel_launch(void* const* d_in, const int* in_sizes, int n_in,
                              void* d_out, int out_size, void* d_ws, size_t ws_size,
                              hipStream_t stream) {
    const float* x  = (const float*)d_in[0];   // [32768][512]
    const float* W  = (const float*)d_in[1];   // [512][512]
    const float* bi = (const float*)d_in[2];   // [512]
    const float* ga = (const float*)d_in[3];   // [512]

    uint8_t* ws = (uint8_t*)d_ws;
    const size_t A_BYTES_BF16 = (size_t)BATCH_N * D_DIM * 2;  // 32MB
    const size_t A_BYTES_F32  = (size_t)BATCH_N * D_DIM * 4;  // 64MB
    const size_t W_BYTES_BF16 = (size_t)1 << 19;              // 512KB slot

    unsigned short* Wb   = (unsigned short*)ws;
    unsigned short* Abf0 = (unsigned short*)(ws + W_BYTES_BF16);
    unsigned short* Abf1 = (unsigned short*)(ws + W_BYTES_BF16 + A_BYTES_BF16);
    float*          Sf   = (float*)(ws + W_BYTES_BF16 + 2 * A_BYTES_BF16);

    const size_t needA = W_BYTES_BF16 + 2 * A_BYTES_BF16 + A_BYTES_F32; // ~128.5MB
    const bool modeA = (ws_size >= needA);  // fp32 state chain in ws

    // Convert W (262144 elems) and x (16777216 elems) to bf16.
    f32_to_bf16_vec4<<<(262144 / 4) / 256, 256, 0, stream>>>(W, Wb, 262144 / 4);
    f32_to_bf16_vec4<<<(16777216 / 4) / 256, 256, 0, stream>>>(x, Abf0, 16777216 / 4);

    const float* sin_f = x;
    unsigned short* ain  = Abf0;
    unsigned short* aout = Abf1;
    dim3 grid(4, 256);

    for (int s = 1; s <= NSTEPS; ++s) {
        float* fout;
        if (modeA)
            fout = (s & 1) ? Sf : (float*)d_out;   // step 50 (even) -> d_out
        else
            fout = (s == NSTEPS) ? (float*)d_out : nullptr;
        unsigned short* abf_out = (s == NSTEPS) ? nullptr : aout;

        node_step<<<grid, 256, 0, stream>>>(ain, Wb, sin_f, bi, ga, fout, abf_out);

        sin_f = modeA ? (const float*)fout : nullptr;
        unsigned short* t = ain; ain = aout; aout = t;
    }
}